// Round 4
// baseline (412.354 us; speedup 1.0000x reference)
//
#include <hip/hip_runtime.h>

// Problem constants
#define NB     64      // batch
#define TT     2048    // time
#define INQ    8       // input size
#define CC     2       // channels
#define MM     10      // hidden m
#define TS     2047    // time steps = T-1
#define ROWP   12      // padded row floats (48 B, 16-aligned)
#define MATP   (MM*ROWP)   // 120 floats per padded matrix
#define SLEN   4       // sequential steps per lane-pair segment
#define SEGS   128     // segments per block
#define CHUNK  (SEGS*SLEN) // 512 steps per block
#define NCHUNK 4       // chunks per chain
#define NCHAIN (NB*CC)
#define KTAY   7       // Taylor order

__device__ __forceinline__ float dpp_xor1(float v) {
    // swap with partner lane (lane ^ 1) via DPP quad_perm [1,0,3,2] = 0xB1
    int i = __float_as_int(v);
    int r = __builtin_amdgcn_update_dpp(i, i, 0xB1, 0xF, 0xF, true);
    return __int_as_float(r);
}

// Upper-triangle index for (k,j), k<j, into 45-element array
__device__ __forceinline__ constexpr int triIdx(int k, int j) {
    return k * 10 + j - ((k + 1) * (k + 2)) / 2;
}

// One block per (chain, chunk). Lane pair processes SLEN steps serially:
// R <- R * expm(G_t) via row-independent S-Horner with G stored as its
// 45-value upper triangle in registers (skew-symmetry; lower = -upper via
// FMA negate modifiers). Then 7-level dyadic LDS tree -> chunk product.
// __launch_bounds__(256, 2): min 2 waves/EU -> VGPR budget 256 (LDS already
// caps us at 2 blocks/CU, so the extra registers are free). Round-3's
// amdgpu_waves_per_eu attribute did NOT raise the budget (VGPR stayed 128,
// ~200-300 MB of scratch spill traffic); this is the documented knob.
__global__ __launch_bounds__(256, 2)
void dev_serial(const float* __restrict__ x,
                const float* __restrict__ A,
                float* __restrict__ ws)
{
    __shared__ float skew_s[INQ * MATP];   // 3840 B
    __shared__ float tree_s[SEGS * MATP];  // 61440 B (total 65280 <= 64 KiB)

    const int tid   = threadIdx.x;
    const int chain = blockIdx.x >> 2;   // / NCHUNK
    const int chunk = blockIdx.x & 3;
    const int n     = chain >> 1;        // / CC
    const int c     = chain & 1;

    // Stage skew = A - A^T for our channel, padded rows (pad = 0)
    for (int e = tid; e < INQ * MATP; e += 256) {
        const int ip  = e / MATP;
        const int rem = e - ip * MATP;
        const int i   = rem / ROWP;
        const int j   = rem - i * ROWP;
        float v = 0.0f;
        if (j < MM) {
            const float* Ab = A + (size_t)(c * INQ + ip) * (MM * MM);
            v = Ab[i * MM + j] - Ab[j * MM + i];
        }
        skew_s[e] = v;
    }
    __syncthreads();

    const int seg = tid >> 1;
    const int p   = tid & 1;     // parity: this lane owns global rows r0..r0+4
    const int r0  = p * 5;

    // Running product rows (identity init)
    float R[5][MM];
    #pragma unroll
    for (int r = 0; r < 5; ++r)
        #pragma unroll
        for (int j = 0; j < MM; ++j)
            R[r][j] = (j == r0 + r) ? 1.0f : 0.0f;

    const float* xb = x + (size_t)n * TT * INQ;
    int t = chunk * CHUNK + seg * SLEN;

    float xc[INQ];
    {
        const float4* xp = reinterpret_cast<const float4*>(xb + (size_t)t * INQ);
        float4 a = xp[0], b = xp[1];
        xc[0] = a.x; xc[1] = a.y; xc[2] = a.z; xc[3] = a.w;
        xc[4] = b.x; xc[5] = b.y; xc[6] = b.z; xc[7] = b.w;
    }

    #pragma unroll 1
    for (int s = 0; s < SLEN; ++s) {
        // next x (clamped: t+1 == 2048 -> reuse last -> dx = 0 -> E = I)
        int tn = t + 1; if (tn > TS) tn = TS;
        float dx[INQ];
        {
            const float4* xp = reinterpret_cast<const float4*>(xb + (size_t)tn * INQ);
            float4 a = xp[0], b = xp[1];
            dx[0] = a.x - xc[0]; dx[1] = a.y - xc[1]; dx[2] = a.z - xc[2]; dx[3] = a.w - xc[3];
            dx[4] = b.x - xc[4]; dx[5] = b.y - xc[5]; dx[6] = b.z - xc[6]; dx[7] = b.w - xc[7];
            xc[0] = a.x; xc[1] = a.y; xc[2] = a.z; xc[3] = a.w;
            xc[4] = b.x; xc[5] = b.y; xc[6] = b.z; xc[7] = b.w;
        }
        t = t + 1;

        // Build gm[s][j] for j > s only. Register gm[s][j] holds, on lane p,
        // G[r0+s][j] (row r0+s of G). Lane 0 needs j>s of its rows; lane 1
        // needs j>5+s of its rows; union j>s computed (lane1's extras unused).
        float gm[5][MM];
        #pragma unroll
        for (int r = 0; r < 5; ++r)
            #pragma unroll
            for (int j = 0; j < MM; ++j)
                if (j > r) gm[r][j] = 0.0f;
        #pragma unroll
        for (int ip = 0; ip < INQ; ++ip) {
            const float d = dx[ip];
            #pragma unroll
            for (int r = 0; r < 5; ++r) {
                const float4* srow = reinterpret_cast<const float4*>(
                    &skew_s[(ip * MM + r0 + r) * ROWP]);
                float4 s0 = srow[0], s1 = srow[1], s2 = srow[2];
                float row[MM] = {s0.x, s0.y, s0.z, s0.w, s1.x, s1.y, s1.z, s1.w, s2.x, s2.y};
                #pragma unroll
                for (int j = 0; j < MM; ++j)
                    if (j > r) gm[r][j] += d * row[j];
            }
        }

        // Assemble upper triangle Tri[45] of G via pair exchange.
        // Register gm[s][j]: lane0 = G[s][j], lane1 = G[5+s][j].
        // Tri[k=s][j]    (k<5):       lane0 own,  lane1 received
        // Tri[k=5+s][j]  (j>5+s):     lane0 received, lane1 own
        float Tri[45];
        #pragma unroll
        for (int sI = 0; sI < 5; ++sI) {
            #pragma unroll
            for (int j = sI + 1; j < MM; ++j) {
                const float own = gm[sI][j];
                const float rec = dpp_xor1(own);
                Tri[triIdx(sI, j)] = p ? rec : own;
                if (j > 5 + sI)
                    Tri[triIdx(5 + sI, j)] = p ? own : rec;
            }
        }

        // S-Horner: S = R; for jt=KTAY..1: S = R + S*G/jt   (row-independent)
        float S[5][MM];
        #pragma unroll
        for (int r = 0; r < 5; ++r)
            #pragma unroll
            for (int j = 0; j < MM; ++j)
                S[r][j] = R[r][j];

        #pragma unroll 1
        for (int jt = KTAY; jt >= 1; --jt) {
            const float inv = 1.0f / (float)jt;
            #pragma unroll
            for (int i = 0; i < 5; ++i) {
                float tr[MM];
                #pragma unroll
                for (int j = 0; j < MM; ++j) tr[j] = 0.0f;
                #pragma unroll
                for (int k = 0; k < MM; ++k) {
                    const float sv = S[i][k];
                    #pragma unroll
                    for (int j = 0; j < MM; ++j) {
                        if (j > k)      tr[j] += sv * Tri[triIdx(k, j)];
                        else if (j < k) tr[j] -= sv * Tri[triIdx(j, k)];
                    }
                }
                #pragma unroll
                for (int j = 0; j < MM; ++j)
                    S[i][j] = fmaf(tr[j], inv, R[i][j]);
            }
        }

        // R <- S
        #pragma unroll
        for (int r = 0; r < 5; ++r)
            #pragma unroll
            for (int j = 0; j < MM; ++j)
                R[r][j] = S[r][j];
    }

    // Store segment product to tree (padded rows, pad = 0)
    {
        float* dst = &tree_s[seg * MATP + r0 * ROWP];
        #pragma unroll
        for (int r = 0; r < 5; ++r) {
            float4* drow = reinterpret_cast<float4*>(dst + r * ROWP);
            drow[0] = make_float4(R[r][0], R[r][1], R[r][2], R[r][3]);
            drow[1] = make_float4(R[r][4], R[r][5], R[r][6], R[r][7]);
            drow[2] = make_float4(R[r][8], R[r][9], 0.0f, 0.0f);
        }
    }
    __syncthreads();

    // Dyadic tree: 7 levels; slot[q*span] <- slot[q*span] * slot[q*span+span/2]
    #pragma unroll 1
    for (int span = 2; span <= SEGS; span <<= 1) {
        const int np = SEGS / span;        // products this level
        if (tid < 2 * np) {
            const int q  = tid >> 1;
            const int pq = tid & 1;
            const int ls = q * span;
            const int rs = ls + (span >> 1);

            float lrow[5][MM];
            #pragma unroll
            for (int r = 0; r < 5; ++r) {
                const float4* lr = reinterpret_cast<const float4*>(
                    &tree_s[ls * MATP + (pq * 5 + r) * ROWP]);
                float4 a = lr[0], b = lr[1], c4 = lr[2];
                lrow[r][0] = a.x;  lrow[r][1] = a.y;  lrow[r][2] = a.z;  lrow[r][3] = a.w;
                lrow[r][4] = b.x;  lrow[r][5] = b.y;  lrow[r][6] = b.z;  lrow[r][7] = b.w;
                lrow[r][8] = c4.x; lrow[r][9] = c4.y;
            }

            float d[5][MM];
            #pragma unroll
            for (int r = 0; r < 5; ++r)
                #pragma unroll
                for (int j = 0; j < MM; ++j)
                    d[r][j] = 0.0f;

            #pragma unroll
            for (int k = 0; k < MM; ++k) {
                const float4* rr = reinterpret_cast<const float4*>(
                    &tree_s[rs * MATP + k * ROWP]);
                float4 a = rr[0], b = rr[1], c4 = rr[2];
                float rrow[MM];
                rrow[0] = a.x;  rrow[1] = a.y;  rrow[2] = a.z;  rrow[3] = a.w;
                rrow[4] = b.x;  rrow[5] = b.y;  rrow[6] = b.z;  rrow[7] = b.w;
                rrow[8] = c4.x; rrow[9] = c4.y;
                #pragma unroll
                for (int r = 0; r < 5; ++r) {
                    const float lv = lrow[r][k];
                    #pragma unroll
                    for (int j = 0; j < MM; ++j)
                        d[r][j] += lv * rrow[j];
                }
            }

            float* dst = &tree_s[ls * MATP + pq * 5 * ROWP];
            #pragma unroll
            for (int r = 0; r < 5; ++r) {
                float4* drow = reinterpret_cast<float4*>(dst + r * ROWP);
                drow[0] = make_float4(d[r][0], d[r][1], d[r][2], d[r][3]);
                drow[1] = make_float4(d[r][4], d[r][5], d[r][6], d[r][7]);
                drow[2] = make_float4(d[r][8], d[r][9], 0.0f, 0.0f);
            }
        }
        __syncthreads();
    }

    // slot 0 = chunk product -> ws (unpadded 100 floats)
    if (tid < 100) {
        const int i = tid / 10;
        const int j = tid - i * 10;
        ws[((size_t)chain * NCHUNK + chunk) * 100 + tid] = tree_s[i * ROWP + j];
    }
}

// Combine NCHUNK chunk products per chain. One thread per (chain, row).
__global__ __launch_bounds__(256) void dev_combine(const float* __restrict__ ws,
                                                   float* __restrict__ out)
{
    const int id = blockIdx.x * 256 + threadIdx.x;
    if (id >= NCHAIN * MM) return;
    const int chain = id / MM;
    const int r     = id - chain * MM;

    const float* base = ws + (size_t)chain * NCHUNK * 100;
    float R[MM];
    #pragma unroll
    for (int j = 0; j < MM; ++j) R[j] = base[r * MM + j];

    #pragma unroll
    for (int ck = 1; ck < NCHUNK; ++ck) {
        const float* Mb = base + ck * 100;
        float Rn[MM];
        #pragma unroll
        for (int j = 0; j < MM; ++j) Rn[j] = 0.0f;
        #pragma unroll
        for (int k = 0; k < MM; ++k) {
            const float rv = R[k];
            #pragma unroll
            for (int j = 0; j < MM; ++j)
                Rn[j] += rv * Mb[k * MM + j];
        }
        #pragma unroll
        for (int j = 0; j < MM; ++j) R[j] = Rn[j];
    }

    #pragma unroll
    for (int j = 0; j < MM; ++j)
        out[(size_t)chain * 100 + r * MM + j] = R[j];
}

extern "C" void kernel_launch(void* const* d_in, const int* in_sizes, int n_in,
                              void* d_out, int out_size, void* d_ws, size_t ws_size,
                              hipStream_t stream) {
    (void)in_sizes; (void)n_in; (void)out_size; (void)ws_size;
    const float* x = (const float*)d_in[0];  // (64, 2048, 8)
    const float* A = (const float*)d_in[1];  // (2, 8, 10, 10)
    float* out = (float*)d_out;              // (64, 2, 10, 10)
    float* ws  = (float*)d_ws;               // 128*4*100 floats = 204800 B

    dev_serial<<<dim3(NCHAIN * NCHUNK), dim3(256), 0, stream>>>(x, A, ws);
    dev_combine<<<dim3((NCHAIN * MM + 255) / 256), dim3(256), 0, stream>>>(ws, out);
}

// Round 6
// 166.672 us; speedup vs baseline: 2.4740x; 2.4740x over previous
//
#include <hip/hip_runtime.h>

// Problem constants
#define NB     64      // batch
#define TT     2048    // time
#define INQ    8       // input size
#define CC     2       // channels
#define MM     10      // hidden m
#define ROWP   12      // padded row floats (48 B)
#define MATP   (MM*ROWP)   // 120 floats per padded matrix
#define SLEN   4       // sequential steps per quad segment
#define SEGS   64      // segments per block (256 thr / 4 lanes)
#define CSTEPS (SEGS*SLEN) // 256 steps per block
#define NCHUNK 8       // chunks per chain
#define NCHAIN (NB*CC)
#define KTAY   7       // Taylor order

// Upper-triangle index for (k,j), k<j, into 45-element array
__device__ __forceinline__ constexpr int triIdx(int k, int j) {
    return k * 10 + j - ((k + 1) * (k + 2)) / 2;
}

// Broadcast lane (quad base + SRC)'s value to all 4 lanes of the quad.
// quad_perm ctl [SRC,SRC,SRC,SRC] = SRC * 0b01010101 = SRC * 0x55.
template <int SRC>
__device__ __forceinline__ float dpp_qbcast(float v) {
    const int i = __float_as_int(v);
    const int r = __builtin_amdgcn_update_dpp(i, i, SRC * 0x55, 0xF, 0xF, true);
    return __int_as_float(r);
}

// One block per (chain, chunk). Each lane QUAD owns one segment of SLEN
// sequential steps; rows of R split 3/3/2/2 across the quad so the Taylor
// live set (R 30 + Acc 30 + Tri 45 + tr 10) fits the 128-VGPR budget the
// allocator pins us to (rounds 2-4: bigger live sets -> scratch spills ->
// 12% VALUBusy). Each lane computes 12 of the 45 upper-triangle values of
// G from a precomputed (45x8) sktri table; the full Tri[45] is assembled
// per-lane with 45 DPP quad-broadcasts (round 5's LDS exchange overlapped
// the tree buffer -> inter-wave race; DPP is register-only and race-free).
// R <- R*expm(G) via fused Acc-Horner with ASCENDING jt (descending was
// round 5's series bug). LDS ~31.5 KB -> 4 blocks/CU with 128 VGPRs.
__global__ __launch_bounds__(256)
void dev_serial(const float* __restrict__ x,
                const float* __restrict__ A,
                float* __restrict__ ws)
{
    __shared__ __align__(16) float sk_s[48 * INQ];   // 1536 B (t>=45 zero)
    __shared__ __align__(16) float buf_s[SEGS * MATP]; // 30720 B tree buffer

    const int tid   = threadIdx.x;
    const int chain = blockIdx.x >> 3;   // / NCHUNK
    const int chunk = blockIdx.x & 7;
    const int n     = chain >> 1;        // / CC
    const int c     = chain & 1;

    // Precompute sktri[t][ip] = A[c][ip][k][j] - A[c][ip][j][k], t <-> (k<j)
    for (int e = tid; e < 48 * INQ; e += 256) {
        const int t  = e >> 3;
        const int ip = e & 7;
        float v = 0.0f;
        if (t < 45) {
            int k = 0, rem = t;
            while (rem >= 9 - k) { rem -= (9 - k); ++k; }
            const int j = k + 1 + rem;
            const float* Ab = A + (size_t)(c * INQ + ip) * (MM * MM);
            v = Ab[k * MM + j] - Ab[j * MM + k];
        }
        sk_s[e] = v;
    }
    __syncthreads();

    const int seg = tid >> 2;
    const int q   = tid & 3;                       // lane within quad
    const int r0  = (q < 2) ? 3 * q : (q == 2 ? 6 : 8);
    const int rc  = (q < 2) ? 3 : 2;               // real rows owned

    // Running product rows (identity; dummy 3rd row on q>=2 lanes is
    // computed but never stored)
    float R[3][MM];
    #pragma unroll
    for (int r = 0; r < 3; ++r) {
        const int gi = (r0 + r > 9) ? 9 : (r0 + r);
        #pragma unroll
        for (int j = 0; j < MM; ++j)
            R[r][j] = (j == gi) ? 1.0f : 0.0f;
    }

    const float* xb = x + (size_t)n * TT * INQ;
    const int t0 = chunk * CSTEPS + seg * SLEN;

    #pragma unroll 1
    for (int s = 0; s < SLEN; ++s) {
        const int t  = t0 + s;
        int tn = t + 1; if (tn > TT - 1) tn = TT - 1;   // pad step -> dx=0 -> E=I
        const float4* xpa = reinterpret_cast<const float4*>(xb + (size_t)t  * INQ);
        const float4* xpb = reinterpret_cast<const float4*>(xb + (size_t)tn * INQ);
        const float4 a0 = xpa[0], a1 = xpa[1];
        const float4 b0 = xpb[0], b1 = xpb[1];
        float dx[INQ];
        dx[0] = b0.x - a0.x; dx[1] = b0.y - a0.y; dx[2] = b0.z - a0.z; dx[3] = b0.w - a0.w;
        dx[4] = b1.x - a1.x; dx[5] = b1.y - a1.y; dx[6] = b1.z - a1.z; dx[7] = b1.w - a1.w;

        // My 12 tri values: tv[u] = sum_ip dx[ip] * sktri[q*12+u][ip]
        float tv[12];
        #pragma unroll
        for (int u = 0; u < 12; ++u) {
            const float4* sp = reinterpret_cast<const float4*>(&sk_s[(q * 12 + u) * INQ]);
            const float4 s0 = sp[0], s1 = sp[1];
            tv[u] = dx[0] * s0.x + dx[1] * s0.y + dx[2] * s0.z + dx[3] * s0.w
                  + dx[4] * s1.x + dx[5] * s1.y + dx[6] * s1.z + dx[7] * s1.w;
        }

        // Assemble full Tri[45] per-lane via DPP quad broadcast:
        // global tri index U was computed by quad-lane U/12 at tv[U%12].
        float Tri[45];
        #define TRIFILL(U) Tri[U] = dpp_qbcast<(U) / 12>(tv[(U) % 12]);
        TRIFILL(0)  TRIFILL(1)  TRIFILL(2)  TRIFILL(3)  TRIFILL(4)
        TRIFILL(5)  TRIFILL(6)  TRIFILL(7)  TRIFILL(8)  TRIFILL(9)
        TRIFILL(10) TRIFILL(11) TRIFILL(12) TRIFILL(13) TRIFILL(14)
        TRIFILL(15) TRIFILL(16) TRIFILL(17) TRIFILL(18) TRIFILL(19)
        TRIFILL(20) TRIFILL(21) TRIFILL(22) TRIFILL(23) TRIFILL(24)
        TRIFILL(25) TRIFILL(26) TRIFILL(27) TRIFILL(28) TRIFILL(29)
        TRIFILL(30) TRIFILL(31) TRIFILL(32) TRIFILL(33) TRIFILL(34)
        TRIFILL(35) TRIFILL(36) TRIFILL(37) TRIFILL(38) TRIFILL(39)
        TRIFILL(40) TRIFILL(41) TRIFILL(42) TRIFILL(43) TRIFILL(44)
        #undef TRIFILL

        // Fused Acc-Horner, ASCENDING jt (term_j = R * G^j / j!):
        // Acc = R; for jt=1..K: Acc <- Acc*(G/jt); R += Acc
        // G[k][j] = Tri[triIdx(k,j)] for k<j, -Tri[triIdx(j,k)] for k>j, 0 diag.
        float Acc[3][MM];
        #pragma unroll
        for (int r = 0; r < 3; ++r)
            #pragma unroll
            for (int j = 0; j < MM; ++j)
                Acc[r][j] = R[r][j];

        #pragma unroll 1
        for (int jt = 1; jt <= KTAY; ++jt) {
            const float inv = 1.0f / (float)jt;
            #pragma unroll
            for (int r = 0; r < 3; ++r) {
                float tr[MM];
                #pragma unroll
                for (int j = 0; j < MM; ++j) tr[j] = 0.0f;
                #pragma unroll
                for (int k = 0; k < MM; ++k) {
                    const float av = Acc[r][k];
                    #pragma unroll
                    for (int j = 0; j < MM; ++j) {
                        if (j > k)      tr[j] += av * Tri[triIdx(k, j)];
                        else if (j < k) tr[j] -= av * Tri[triIdx(j, k)];
                    }
                }
                #pragma unroll
                for (int j = 0; j < MM; ++j) {
                    const float nv = tr[j] * inv;
                    Acc[r][j] = nv;
                    R[r][j]  += nv;
                }
            }
        }
    }

    // Store segment product (real rows only) into tree region
    {
        float* dst = &buf_s[seg * MATP];
        #pragma unroll
        for (int r = 0; r < 3; ++r) {
            if (r < rc) {
                float4* drow = reinterpret_cast<float4*>(dst + (r0 + r) * ROWP);
                drow[0] = make_float4(R[r][0], R[r][1], R[r][2], R[r][3]);
                drow[1] = make_float4(R[r][4], R[r][5], R[r][6], R[r][7]);
                drow[2] = make_float4(R[r][8], R[r][9], 0.0f, 0.0f);
            }
        }
    }
    __syncthreads();

    // Pair-style dyadic tree over 64 segment products (6 levels)
    #pragma unroll 1
    for (int span = 2; span <= SEGS; span <<= 1) {
        const int np = SEGS / span;
        if (tid < 2 * np) {
            const int pr = tid >> 1;
            const int pq = tid & 1;
            const int ls = pr * span;
            const int rs = ls + (span >> 1);

            float lrow[5][MM];
            #pragma unroll
            for (int r = 0; r < 5; ++r) {
                const float4* lr = reinterpret_cast<const float4*>(
                    &buf_s[ls * MATP + (pq * 5 + r) * ROWP]);
                const float4 a = lr[0], b = lr[1], c4 = lr[2];
                lrow[r][0] = a.x;  lrow[r][1] = a.y;  lrow[r][2] = a.z;  lrow[r][3] = a.w;
                lrow[r][4] = b.x;  lrow[r][5] = b.y;  lrow[r][6] = b.z;  lrow[r][7] = b.w;
                lrow[r][8] = c4.x; lrow[r][9] = c4.y;
            }

            float d[5][MM];
            #pragma unroll
            for (int r = 0; r < 5; ++r)
                #pragma unroll
                for (int j = 0; j < MM; ++j)
                    d[r][j] = 0.0f;

            #pragma unroll
            for (int k = 0; k < MM; ++k) {
                const float4* rr = reinterpret_cast<const float4*>(
                    &buf_s[rs * MATP + k * ROWP]);
                const float4 a = rr[0], b = rr[1], c4 = rr[2];
                float rrow[MM];
                rrow[0] = a.x;  rrow[1] = a.y;  rrow[2] = a.z;  rrow[3] = a.w;
                rrow[4] = b.x;  rrow[5] = b.y;  rrow[6] = b.z;  rrow[7] = b.w;
                rrow[8] = c4.x; rrow[9] = c4.y;
                #pragma unroll
                for (int r = 0; r < 5; ++r) {
                    const float lv = lrow[r][k];
                    #pragma unroll
                    for (int j = 0; j < MM; ++j)
                        d[r][j] += lv * rrow[j];
                }
            }

            float* dst = &buf_s[ls * MATP + pq * 5 * ROWP];
            #pragma unroll
            for (int r = 0; r < 5; ++r) {
                float4* drow = reinterpret_cast<float4*>(dst + r * ROWP);
                drow[0] = make_float4(d[r][0], d[r][1], d[r][2], d[r][3]);
                drow[1] = make_float4(d[r][4], d[r][5], d[r][6], d[r][7]);
                drow[2] = make_float4(d[r][8], d[r][9], 0.0f, 0.0f);
            }
        }
        __syncthreads();
    }

    // slot 0 = chunk product -> ws (unpadded 100 floats)
    if (tid < 100) {
        const int i = tid / 10;
        const int j = tid - i * 10;
        ws[((size_t)chain * NCHUNK + chunk) * 100 + tid] = buf_s[i * ROWP + j];
    }
}

// Combine NCHUNK chunk products per chain. One thread per (chain, row).
__global__ __launch_bounds__(256) void dev_combine(const float* __restrict__ ws,
                                                   float* __restrict__ out)
{
    const int id = blockIdx.x * 256 + threadIdx.x;
    if (id >= NCHAIN * MM) return;
    const int chain = id / MM;
    const int r     = id - chain * MM;

    const float* base = ws + (size_t)chain * NCHUNK * 100;
    float R[MM];
    #pragma unroll
    for (int j = 0; j < MM; ++j) R[j] = base[r * MM + j];

    #pragma unroll 1
    for (int ck = 1; ck < NCHUNK; ++ck) {
        const float* Mb = base + ck * 100;
        float Rn[MM];
        #pragma unroll
        for (int j = 0; j < MM; ++j) Rn[j] = 0.0f;
        #pragma unroll
        for (int k = 0; k < MM; ++k) {
            const float rv = R[k];
            #pragma unroll
            for (int j = 0; j < MM; ++j)
                Rn[j] += rv * Mb[k * MM + j];
        }
        #pragma unroll
        for (int j = 0; j < MM; ++j) R[j] = Rn[j];
    }

    #pragma unroll
    for (int j = 0; j < MM; ++j)
        out[(size_t)chain * 100 + r * MM + j] = R[j];
}

extern "C" void kernel_launch(void* const* d_in, const int* in_sizes, int n_in,
                              void* d_out, int out_size, void* d_ws, size_t ws_size,
                              hipStream_t stream) {
    (void)in_sizes; (void)n_in; (void)out_size; (void)ws_size;
    const float* x = (const float*)d_in[0];  // (64, 2048, 8)
    const float* A = (const float*)d_in[1];  // (2, 8, 10, 10)
    float* out = (float*)d_out;              // (64, 2, 10, 10)
    float* ws  = (float*)d_ws;               // 128*8*100 floats = 409600 B

    dev_serial<<<dim3(NCHAIN * NCHUNK), dim3(256), 0, stream>>>(x, A, ws);
    dev_combine<<<dim3((NCHAIN * MM + 255) / 256), dim3(256), 0, stream>>>(ws, out);
}

// Round 7
// 163.885 us; speedup vs baseline: 2.5161x; 1.0170x over previous
//
#include <hip/hip_runtime.h>

// Problem constants
#define NB     64      // batch
#define TT     2048    // time
#define INQ    8       // input size
#define CC     2       // channels
#define MM     10      // hidden m
#define ROWP   12      // padded row floats (48 B)
#define MATS   124     // matrix stride in tree buffer (124%32=28 -> lvl1 8-way not 16-way)
#define SKSTR  12      // sktri row stride floats (quad lanes 144 words apart = 2-way = free)
#define SLEN   6       // sequential steps per quad segment
#define SEGS   64      // segments per block (256 thr / 4 lanes)
#define CSTEPS (SEGS*SLEN) // 384 steps per block
#define NCHUNK 6       // chunks per chain -> grid 768 = exactly 3 blocks/CU at 136 VGPR
#define NCHAIN (NB*CC)
#define KTAY   7       // Taylor order (validated absmax 3.9e-3 vs thr 1.95e-2)

// Upper-triangle index for (k,j), k<j, into 45-element array
__device__ __forceinline__ constexpr int triIdx(int k, int j) {
    return k * 10 + j - ((k + 1) * (k + 2)) / 2;
}

// Broadcast lane (quad base + SRC)'s value to all 4 lanes of the quad.
template <int SRC>
__device__ __forceinline__ float dpp_qbcast(float v) {
    const int i = __float_as_int(v);
    const int r = __builtin_amdgcn_update_dpp(i, i, SRC * 0x55, 0xF, 0xF, true);
    return __int_as_float(r);
}

// One block per (chain, chunk). Quad owns a segment of SLEN sequential steps,
// rows split 3/3/2/2 so Taylor live set (R30+Acc30+Tri45+tr10) fits the
// 128-136 VGPR envelope without spills (r6: VGPR=136, no scratch traffic).
// Round 6 ran grid=4/CU against 3-blocks/CU residency -> two dispatch rounds,
// VALUBusy 46%. This round: NCHUNK=6/SLEN=6 -> grid 768 = exactly 3/CU,
// one balanced round. sk rows padded to 12 floats (kills the 4-way quad
// bank conflict: 2.48M conflict cycles in r6), tree stride 124.
__global__ __launch_bounds__(256)
void dev_serial(const float* __restrict__ x,
                const float* __restrict__ A,
                float* __restrict__ ws)
{
    __shared__ __align__(16) float sk_s[48 * SKSTR];    // 2304 B (rows >=45 zero)
    __shared__ __align__(16) float buf_s[SEGS * MATS];  // 31744 B tree buffer

    const int tid   = threadIdx.x;
    const int chain = blockIdx.x / NCHUNK;
    const int chunk = blockIdx.x - chain * NCHUNK;
    const int n     = chain >> 1;        // / CC
    const int c     = chain & 1;

    // Precompute sktri[t][ip] = A[c][ip][k][j] - A[c][ip][j][k], t <-> (k<j)
    for (int e = tid; e < 48 * INQ; e += 256) {
        const int t  = e >> 3;
        const int ip = e & 7;
        float v = 0.0f;
        if (t < 45) {
            int k = 0, rem = t;
            while (rem >= 9 - k) { rem -= (9 - k); ++k; }
            const int j = k + 1 + rem;
            const float* Ab = A + (size_t)(c * INQ + ip) * (MM * MM);
            v = Ab[k * MM + j] - Ab[j * MM + k];
        }
        sk_s[t * SKSTR + ip] = v;
    }
    // zero the 4-float pad of each row (read by float4 loads, must be defined)
    for (int t = tid; t < 48; t += 256) {
        sk_s[t * SKSTR + 8]  = 0.0f; sk_s[t * SKSTR + 9]  = 0.0f;
        sk_s[t * SKSTR + 10] = 0.0f; sk_s[t * SKSTR + 11] = 0.0f;
    }
    __syncthreads();

    const int seg = tid >> 2;
    const int q   = tid & 3;                       // lane within quad
    const int r0  = (q < 2) ? 3 * q : (q == 2 ? 6 : 8);
    const int rc  = (q < 2) ? 3 : 2;               // real rows owned

    // Running product rows (identity; dummy 3rd row on q>=2 lanes is
    // computed but never stored)
    float R[3][MM];
    #pragma unroll
    for (int r = 0; r < 3; ++r) {
        const int gi = (r0 + r > 9) ? 9 : (r0 + r);
        #pragma unroll
        for (int j = 0; j < MM; ++j)
            R[r][j] = (j == gi) ? 1.0f : 0.0f;
    }

    const float* xb = x + (size_t)n * TT * INQ;
    const int t0 = chunk * CSTEPS + seg * SLEN;

    #pragma unroll 1
    for (int s = 0; s < SLEN; ++s) {
        // clamp BOTH indices: chunks now over-cover (2304 > 2047); t can
        // exceed the buffer. ta==tn -> dx=0 -> E=I for pad steps.
        int ta = t0 + s;       if (ta > TT - 1) ta = TT - 1;
        int tn = t0 + s + 1;   if (tn > TT - 1) tn = TT - 1;
        const float4* xpa = reinterpret_cast<const float4*>(xb + (size_t)ta * INQ);
        const float4* xpb = reinterpret_cast<const float4*>(xb + (size_t)tn * INQ);
        const float4 a0 = xpa[0], a1 = xpa[1];
        const float4 b0 = xpb[0], b1 = xpb[1];
        float dx[INQ];
        dx[0] = b0.x - a0.x; dx[1] = b0.y - a0.y; dx[2] = b0.z - a0.z; dx[3] = b0.w - a0.w;
        dx[4] = b1.x - a1.x; dx[5] = b1.y - a1.y; dx[6] = b1.z - a1.z; dx[7] = b1.w - a1.w;

        // My 12 tri values: tv[u] = sum_ip dx[ip] * sktri[q*12+u][ip]
        float tv[12];
        #pragma unroll
        for (int u = 0; u < 12; ++u) {
            const float4* sp = reinterpret_cast<const float4*>(&sk_s[(q * 12 + u) * SKSTR]);
            const float4 s0 = sp[0], s1 = sp[1];
            tv[u] = dx[0] * s0.x + dx[1] * s0.y + dx[2] * s0.z + dx[3] * s0.w
                  + dx[4] * s1.x + dx[5] * s1.y + dx[6] * s1.z + dx[7] * s1.w;
        }

        // Assemble full Tri[45] per-lane via DPP quad broadcast:
        // global tri index U was computed by quad-lane U/12 at tv[U%12].
        float Tri[45];
        #define TRIFILL(U) Tri[U] = dpp_qbcast<(U) / 12>(tv[(U) % 12]);
        TRIFILL(0)  TRIFILL(1)  TRIFILL(2)  TRIFILL(3)  TRIFILL(4)
        TRIFILL(5)  TRIFILL(6)  TRIFILL(7)  TRIFILL(8)  TRIFILL(9)
        TRIFILL(10) TRIFILL(11) TRIFILL(12) TRIFILL(13) TRIFILL(14)
        TRIFILL(15) TRIFILL(16) TRIFILL(17) TRIFILL(18) TRIFILL(19)
        TRIFILL(20) TRIFILL(21) TRIFILL(22) TRIFILL(23) TRIFILL(24)
        TRIFILL(25) TRIFILL(26) TRIFILL(27) TRIFILL(28) TRIFILL(29)
        TRIFILL(30) TRIFILL(31) TRIFILL(32) TRIFILL(33) TRIFILL(34)
        TRIFILL(35) TRIFILL(36) TRIFILL(37) TRIFILL(38) TRIFILL(39)
        TRIFILL(40) TRIFILL(41) TRIFILL(42) TRIFILL(43) TRIFILL(44)
        #undef TRIFILL

        // Fused Acc-Horner, ascending jt (term_j = R * G^j / j!):
        // Acc = R; for jt=1..K: Acc <- Acc*(G/jt); R += Acc
        float Acc[3][MM];
        #pragma unroll
        for (int r = 0; r < 3; ++r)
            #pragma unroll
            for (int j = 0; j < MM; ++j)
                Acc[r][j] = R[r][j];

        #pragma unroll 1
        for (int jt = 1; jt <= KTAY; ++jt) {
            const float inv = 1.0f / (float)jt;
            #pragma unroll
            for (int r = 0; r < 3; ++r) {
                float tr[MM];
                #pragma unroll
                for (int j = 0; j < MM; ++j) tr[j] = 0.0f;
                #pragma unroll
                for (int k = 0; k < MM; ++k) {
                    const float av = Acc[r][k];
                    #pragma unroll
                    for (int j = 0; j < MM; ++j) {
                        if (j > k)      tr[j] += av * Tri[triIdx(k, j)];
                        else if (j < k) tr[j] -= av * Tri[triIdx(j, k)];
                    }
                }
                #pragma unroll
                for (int j = 0; j < MM; ++j) {
                    const float nv = tr[j] * inv;
                    Acc[r][j] = nv;
                    R[r][j]  += nv;
                }
            }
        }
    }

    // Store segment product (real rows only) into tree region
    {
        float* dst = &buf_s[seg * MATS];
        #pragma unroll
        for (int r = 0; r < 3; ++r) {
            if (r < rc) {
                float4* drow = reinterpret_cast<float4*>(dst + (r0 + r) * ROWP);
                drow[0] = make_float4(R[r][0], R[r][1], R[r][2], R[r][3]);
                drow[1] = make_float4(R[r][4], R[r][5], R[r][6], R[r][7]);
                drow[2] = make_float4(R[r][8], R[r][9], 0.0f, 0.0f);
            }
        }
    }
    __syncthreads();

    // Pair-style dyadic tree over 64 segment products (6 levels)
    #pragma unroll 1
    for (int span = 2; span <= SEGS; span <<= 1) {
        const int np = SEGS / span;
        if (tid < 2 * np) {
            const int pr = tid >> 1;
            const int pq = tid & 1;
            const int ls = pr * span;
            const int rs = ls + (span >> 1);

            float lrow[5][MM];
            #pragma unroll
            for (int r = 0; r < 5; ++r) {
                const float4* lr = reinterpret_cast<const float4*>(
                    &buf_s[ls * MATS + (pq * 5 + r) * ROWP]);
                const float4 a = lr[0], b = lr[1], c4 = lr[2];
                lrow[r][0] = a.x;  lrow[r][1] = a.y;  lrow[r][2] = a.z;  lrow[r][3] = a.w;
                lrow[r][4] = b.x;  lrow[r][5] = b.y;  lrow[r][6] = b.z;  lrow[r][7] = b.w;
                lrow[r][8] = c4.x; lrow[r][9] = c4.y;
            }

            float d[5][MM];
            #pragma unroll
            for (int r = 0; r < 5; ++r)
                #pragma unroll
                for (int j = 0; j < MM; ++j)
                    d[r][j] = 0.0f;

            #pragma unroll
            for (int k = 0; k < MM; ++k) {
                const float4* rr = reinterpret_cast<const float4*>(
                    &buf_s[rs * MATS + k * ROWP]);
                const float4 a = rr[0], b = rr[1], c4 = rr[2];
                float rrow[MM];
                rrow[0] = a.x;  rrow[1] = a.y;  rrow[2] = a.z;  rrow[3] = a.w;
                rrow[4] = b.x;  rrow[5] = b.y;  rrow[6] = b.z;  rrow[7] = b.w;
                rrow[8] = c4.x; rrow[9] = c4.y;
                #pragma unroll
                for (int r = 0; r < 5; ++r) {
                    const float lv = lrow[r][k];
                    #pragma unroll
                    for (int j = 0; j < MM; ++j)
                        d[r][j] += lv * rrow[j];
                }
            }

            float* dst = &buf_s[ls * MATS + pq * 5 * ROWP];
            #pragma unroll
            for (int r = 0; r < 5; ++r) {
                float4* drow = reinterpret_cast<float4*>(dst + r * ROWP);
                drow[0] = make_float4(d[r][0], d[r][1], d[r][2], d[r][3]);
                drow[1] = make_float4(d[r][4], d[r][5], d[r][6], d[r][7]);
                drow[2] = make_float4(d[r][8], d[r][9], 0.0f, 0.0f);
            }
        }
        __syncthreads();
    }

    // slot 0 = chunk product -> ws (unpadded 100 floats)
    if (tid < 100) {
        const int i = tid / 10;
        const int j = tid - i * 10;
        ws[((size_t)chain * NCHUNK + chunk) * 100 + tid] = buf_s[i * ROWP + j];
    }
}

// Combine NCHUNK chunk products per chain. One thread per (chain, row).
__global__ __launch_bounds__(256) void dev_combine(const float* __restrict__ ws,
                                                   float* __restrict__ out)
{
    const int id = blockIdx.x * 256 + threadIdx.x;
    if (id >= NCHAIN * MM) return;
    const int chain = id / MM;
    const int r     = id - chain * MM;

    const float* base = ws + (size_t)chain * NCHUNK * 100;
    float R[MM];
    #pragma unroll
    for (int j = 0; j < MM; ++j) R[j] = base[r * MM + j];

    #pragma unroll 1
    for (int ck = 1; ck < NCHUNK; ++ck) {
        const float* Mb = base + ck * 100;
        float Rn[MM];
        #pragma unroll
        for (int j = 0; j < MM; ++j) Rn[j] = 0.0f;
        #pragma unroll
        for (int k = 0; k < MM; ++k) {
            const float rv = R[k];
            #pragma unroll
            for (int j = 0; j < MM; ++j)
                Rn[j] += rv * Mb[k * MM + j];
        }
        #pragma unroll
        for (int j = 0; j < MM; ++j) R[j] = Rn[j];
    }

    #pragma unroll
    for (int j = 0; j < MM; ++j)
        out[(size_t)chain * 100 + r * MM + j] = R[j];
}

extern "C" void kernel_launch(void* const* d_in, const int* in_sizes, int n_in,
                              void* d_out, int out_size, void* d_ws, size_t ws_size,
                              hipStream_t stream) {
    (void)in_sizes; (void)n_in; (void)out_size; (void)ws_size;
    const float* x = (const float*)d_in[0];  // (64, 2048, 8)
    const float* A = (const float*)d_in[1];  // (2, 8, 10, 10)
    float* out = (float*)d_out;              // (64, 2, 10, 10)
    float* ws  = (float*)d_ws;               // 128*6*100 floats = 307200 B

    dev_serial<<<dim3(NCHAIN * NCHUNK), dim3(256), 0, stream>>>(x, A, ws);
    dev_combine<<<dim3((NCHAIN * MM + 255) / 256), dim3(256), 0, stream>>>(ws, out);
}